// Round 4
// baseline (255.208 us; speedup 1.0000x reference)
//
#include <hip/hip_runtime.h>
#include <math.h>

// Problem constants
#define NB 128     // batch
#define NC 128     // channels
#define NN 170     // nodes
#define NT 12      // length
#define MP 176     // padded row stride (16B-aligned rows) for xs/Es/Ed/P
#define BSROW 196  // LDS row stride for staged tiles (196%32==4 -> bank spread)

// Workspace regions (floats)
#define XS_SZ  (NB * NC * MP)   // 2,883,584
#define ESP_SZ (NC * MP)        //    22,528
#define P_SZ   (NB * NN * MP)   // 3,829,760
#define ED_SZ  (NB * NN * MP)   // 3,829,760

// tanh via hw exp+rcp: ~6 VALU ops vs ~30+ for libm tanhf. rel err ~1e-6.
__device__ __forceinline__ float fast_tanh(float x) {
    float cx = fminf(fmaxf(x, -15.f), 15.f);        // avoid inf/inf
    float e  = __expf(2.f * cx);                    // v_exp_f32
    return (e - 1.f) * __builtin_amdgcn_rcpf(e + 1.f);
}

// ---------------------------------------------------------------------------
// K1: xs[b][c][n] = sum_t x[b][c][n][t], written PADDED to stride 176 with
// zeros in cols [170,176). Fully-coalesced wave loads + 9 __shfl gathers.
// Blocks >= 10880 produce Es padded to stride 176 (Esp). Near HBM floor.
// ---------------------------------------------------------------------------
__global__ __launch_bounds__(256) void k1_reduce_pad(const float* __restrict__ x,
                                                     const float* __restrict__ Es,
                                                     float* __restrict__ xs,
                                                     float* __restrict__ Esp) {
    if (blockIdx.x >= 10880) {              // Es padding tail: 88 blocks
        int idx = (blockIdx.x - 10880) * 256 + threadIdx.x;
        if (idx < ESP_SZ) {
            int c = idx / MP, m = idx % MP;
            Esp[idx] = (m < NN) ? Es[c * NN + m] : 0.f;
        }
        return;
    }
    const int w    = blockIdx.x * 4 + (threadIdx.x >> 6);  // global wave id
    const int lane = threadIdx.x & 63;
    const float4* x4 = reinterpret_cast<const float4*>(x) + (size_t)w * 192;
    float4 f0 = x4[lane], f1 = x4[lane + 64], f2 = x4[lane + 128];
    float p0 = (f0.x + f0.y) + (f0.z + f0.w);
    float p1 = (f1.x + f1.y) + (f1.z + f1.w);
    float p2 = (f2.x + f2.y) + (f2.z + f2.w);
    float tot = 0.f;
    #pragma unroll
    for (int j = 0; j < 3; ++j) {
        int s = 3 * lane + j;
        int src = s & 63, reg = s >> 6;
        float a0 = __shfl(p0, src, 64);
        float a1 = __shfl(p1, src, 64);
        float a2 = __shfl(p2, src, 64);
        tot += (reg == 0) ? a0 : (reg == 1) ? a1 : a2;
    }
    int g  = w * 64 + lane;                 // global group in [0, 2785280)
    int bc = g / NN, n = g - bc * NN;
    xs[(size_t)bc * MP + n] = tot;
    if (n < MP - NN) xs[(size_t)bc * MP + NN + n] = 0.f;   // zero the pad cols
}

// ---------------------------------------------------------------------------
// K2: Ed[b][n][m] = tanh( sum_c xs[b][c][n] * Esp[c][m] ), m in [0,176).
// Block = (b, 48-row tile): grid (4,128)=512 = exactly 2 blocks/CU.
// 256 threads as 16tx x 16ty; thread owns rows ty+16*ii (ii<3), cols
// tx*4 + off*64 (off<3). acc[3][12]: 36 FMA per 3 b32 + 3 b128 LDS reads.
// ---------------------------------------------------------------------------
__global__ __launch_bounds__(256) void k2_embed(const float* __restrict__ xs,
                                                const float* __restrict__ Esp,
                                                float* __restrict__ Ed) {
    const int b = blockIdx.y, n0 = blockIdx.x * 48;
    const int t = threadIdx.x, tx = t & 15, ty = t >> 4;
    __shared__ __align__(16) float As[16][52];      // [c][n], 48 rows +4 pad
    __shared__ __align__(16) float Bs[16][BSROW];   // [c][m]

    float acc[3][12] = {};
    for (int c0 = 0; c0 < NC; c0 += 16) {
        __syncthreads();
        if (t < 192) {                               // A: 192 float4 (16c x 48n)
            int c = t / 12, q = t - (t / 12) * 12;   // q*4 in [0,48)
            float4 v = make_float4(0.f, 0.f, 0.f, 0.f);
            if (n0 + q * 4 < MP)                     // n0=144 tile: cols>=176 zero
                v = *reinterpret_cast<const float4*>(
                    xs + ((size_t)(b * NC + c0 + c)) * MP + n0 + q * 4);
            *reinterpret_cast<float4*>(&As[c][q * 4]) = v;
        }
        #pragma unroll
        for (int it = 0; it < 3; ++it) {             // B: 768 float4 (16c x 192m)
            int idx = t + it * 256;
            int c = idx / 48, mq = idx - c * 48;
            float4 v = make_float4(0.f, 0.f, 0.f, 0.f);
            if (mq < 44)
                v = *reinterpret_cast<const float4*>(Esp + (c0 + c) * MP + mq * 4);
            *reinterpret_cast<float4*>(&Bs[c][mq * 4]) = v;
        }
        __syncthreads();
        #pragma unroll
        for (int cc = 0; cc < 16; ++cc) {
            float a[3];
            #pragma unroll
            for (int ii = 0; ii < 3; ++ii) a[ii] = As[cc][ty + 16 * ii];
            float bb[12];
            #pragma unroll
            for (int off = 0; off < 3; ++off) {
                float4 bv = *reinterpret_cast<const float4*>(&Bs[cc][tx * 4 + off * 64]);
                bb[off * 4 + 0] = bv.x; bb[off * 4 + 1] = bv.y;
                bb[off * 4 + 2] = bv.z; bb[off * 4 + 3] = bv.w;
            }
            #pragma unroll
            for (int ii = 0; ii < 3; ++ii)
                #pragma unroll
                for (int jj = 0; jj < 12; ++jj)
                    acc[ii][jj] = fmaf(a[ii], bb[jj], acc[ii][jj]);
        }
    }
    #pragma unroll
    for (int ii = 0; ii < 3; ++ii) {
        int n = n0 + ty + 16 * ii;
        if (n >= NN) continue;
        float* Erow = Ed + ((size_t)(b * NN + n)) * MP;
        #pragma unroll
        for (int off = 0; off < 3; ++off) {
            int m = tx * 4 + off * 64;
            if (m >= MP) continue;                   // off==2 && tx>=12
            float4 v;
            v.x = fast_tanh(acc[ii][off * 4 + 0]);
            v.y = fast_tanh(acc[ii][off * 4 + 1]);
            v.z = fast_tanh(acc[ii][off * 4 + 2]);
            v.w = fast_tanh(acc[ii][off * 4 + 3]);
            *reinterpret_cast<float4*>(Erow + m) = v;
        }
    }
}

// ---------------------------------------------------------------------------
// K3: scores[n][k] = relu( dot_m(Ed[b,n,:], Ed[b,k,:]) / sqrt(C) ), row
// softmax over k<170, P[b][n][k] (stride 176).
// Block = (b, 48-row tile): grid (4,128)=512 = 2 blocks/CU even.
// Single LDS buffer Bs[mm][k] (k<192, zeros past 170) serves BOTH the
// A-fragment (rows r0+ty+16*ii, broadcast b32) and B-fragment (cols, b128).
// acc[3][12]; softmax fully in-register via 16-lane shfl_xor reductions.
// ---------------------------------------------------------------------------
__global__ __launch_bounds__(256) void k3_scores(const float* __restrict__ Ed,
                                                 float* __restrict__ P) {
    const int b = blockIdx.y, r0 = blockIdx.x * 48;
    const int t = threadIdx.x, tx = t & 15, ty = t >> 4;
    __shared__ __align__(16) float Bs[16][BSROW];   // [mm][k]
    const float* __restrict__ Edb = Ed + (size_t)b * NN * MP;

    float acc[3][12] = {};
    for (int mc = 0; mc < MP; mc += 16) {
        __syncthreads();
        #pragma unroll
        for (int it = 0; it < 3; ++it) {             // 768 float4: k<192 x 4 quads
            int idx = t + it * 256;
            int k = idx >> 2, mq = idx & 3;
            float4 v = make_float4(0.f, 0.f, 0.f, 0.f);
            if (k < NN)
                v = *reinterpret_cast<const float4*>(Edb + (size_t)k * MP + mc + mq * 4);
            Bs[mq * 4 + 0][k] = v.x;                 // transposed scalar writes
            Bs[mq * 4 + 1][k] = v.y;
            Bs[mq * 4 + 2][k] = v.z;
            Bs[mq * 4 + 3][k] = v.w;
        }
        __syncthreads();
        #pragma unroll
        for (int mm = 0; mm < 16; ++mm) {
            float a[3];
            #pragma unroll
            for (int ii = 0; ii < 3; ++ii) a[ii] = Bs[mm][r0 + ty + 16 * ii];
            float bb[12];
            #pragma unroll
            for (int off = 0; off < 3; ++off) {
                float4 bv = *reinterpret_cast<const float4*>(&Bs[mm][tx * 4 + off * 64]);
                bb[off * 4 + 0] = bv.x; bb[off * 4 + 1] = bv.y;
                bb[off * 4 + 2] = bv.z; bb[off * 4 + 3] = bv.w;
            }
            #pragma unroll
            for (int ii = 0; ii < 3; ++ii)
                #pragma unroll
                for (int jj = 0; jj < 12; ++jj)
                    acc[ii][jj] = fmaf(a[ii], bb[jj], acc[ii][jj]);
        }
    }

    // In-register softmax. Thread's cols: k = tx*4 + (jj&3) + (jj>>2)*64.
    const float scale = 0.08838834764831845f;        // 1/sqrt(128)
    #pragma unroll
    for (int ii = 0; ii < 3; ++ii) {
        int n = r0 + ty + 16 * ii;
        float vv[12];
        float mx = -1.f;                             // valid scores are >= 0
        #pragma unroll
        for (int jj = 0; jj < 12; ++jj) {
            int k = tx * 4 + (jj & 3) + (jj >> 2) * 64;
            float v = fmaxf(acc[ii][jj] * scale, 0.f);
            vv[jj] = (k < NN) ? v : -1.f;
            mx = fmaxf(mx, vv[jj]);
        }
        #pragma unroll
        for (int off = 8; off; off >>= 1) mx = fmaxf(mx, __shfl_xor(mx, off, 64));
        float ex[12], sum = 0.f;
        #pragma unroll
        for (int jj = 0; jj < 12; ++jj) {
            int k = tx * 4 + (jj & 3) + (jj >> 2) * 64;
            float e = (k < NN) ? __expf(vv[jj] - mx) : 0.f;
            ex[jj] = e;
            sum += e;
        }
        #pragma unroll
        for (int off = 8; off; off >>= 1) sum += __shfl_xor(sum, off, 64);
        float inv = 1.f / sum;
        if (n < NN) {
            float* Pr = P + ((size_t)(b * NN + n)) * MP;
            #pragma unroll
            for (int off = 0; off < 3; ++off) {
                int k = tx * 4 + off * 64;
                if (k >= MP) continue;               // off==2 && tx>=12
                float4 v;                            // cols >=170 are pad: e==0
                v.x = ex[off * 4 + 0] * inv; v.y = ex[off * 4 + 1] * inv;
                v.z = ex[off * 4 + 2] * inv; v.w = ex[off * 4 + 3] * inv;
                *reinterpret_cast<float4*>(Pr + k) = v;
            }
        }
    }
}

// ---------------------------------------------------------------------------
// K4a: batch-partial means -- grid (113, 8); block y sums 16 batches.
// K4b: combine 8 partials + threshold.
// ---------------------------------------------------------------------------
__global__ __launch_bounds__(256) void k4a_partial(const float* __restrict__ P,
                                                   float* __restrict__ Pm) {
    int p = blockIdx.x * 256 + threadIdx.x;
    if (p >= NN * NN) return;
    int n = p / NN, k = p - n * NN;
    const float* base = P + (size_t)blockIdx.y * 16 * NN * MP + (size_t)n * MP + k;
    float s = 0.f;
    #pragma unroll
    for (int b = 0; b < 16; ++b) s += base[(size_t)b * NN * MP];
    Pm[blockIdx.y * (NN * NN) + p] = s;
}

__global__ __launch_bounds__(256) void k4b_thresh(const float* __restrict__ Pm,
                                                  float* __restrict__ out) {
    int p = blockIdx.x * 256 + threadIdx.x;
    if (p >= NN * NN) return;
    float s = 0.f;
    #pragma unroll
    for (int g = 0; g < 8; ++g) s += Pm[g * (NN * NN) + p];
    out[p] = (s * (1.f / 128.f) > 0.5f) ? 1.f : 0.f;
}

// ---------------------------------------------------------------------------
// Workspace layout (floats):
//   [0, P_SZ)            : P (padded 176)  -- first aliased as xs + Esp,
//                          both dead once K2 finishes.
//   [P_SZ, P_SZ+ED_SZ)   : Ed (padded 176) -- reused as Pm by K4a (Ed dead).
// Total = 30.64 MB.
// ---------------------------------------------------------------------------
extern "C" void kernel_launch(void* const* d_in, const int* in_sizes, int n_in,
                              void* d_out, int out_size, void* d_ws, size_t ws_size,
                              hipStream_t stream) {
    const float* x  = (const float*)d_in[0];   // [128,128,170,12] f32
    const float* Es = (const float*)d_in[1];   // [128,170] f32
    float* out = (float*)d_out;                // [170,170] f32
    float* wsf = (float*)d_ws;

    float* P   = wsf;
    float* xs  = wsf;                 // aliases P region
    float* Esp = wsf + XS_SZ;         // aliases P region (tail)
    float* Ed  = wsf + P_SZ;
    float* Pm  = Ed;                  // reuses Ed region after K3

    k1_reduce_pad<<<10968, 256, 0, stream>>>(x, Es, xs, Esp);
    k2_embed<<<dim3(4, 128), 256, 0, stream>>>(xs, Esp, Ed);
    k3_scores<<<dim3(4, 128), 256, 0, stream>>>(Ed, P);
    k4a_partial<<<dim3(113, 8), 256, 0, stream>>>(P, Pm);
    k4b_thresh<<<113, 256, 0, stream>>>(Pm, out);
}